// Round 10
// baseline (457.490 us; speedup 1.0000x reference)
//
#include <hip/hip_runtime.h>

#define NN 100000
#define DIM 128
#define NE 1600000
#define NCHUNK 64
#define FILL_CHUNK (NE / NCHUNK)    // 25000

typedef __attribute__((ext_vector_type(8))) short short8;
typedef __attribute__((ext_vector_type(4))) float f32x4;

// fp32 -> bf16 bits, round-to-nearest-even
__device__ __forceinline__ unsigned f2b(float f) {
    unsigned u = __float_as_uint(f);
    return (u + 0x7FFFu + ((u >> 16) & 1u)) >> 16;
}
__device__ __forceinline__ float blo(unsigned v) { return __uint_as_float(v << 16); }
__device__ __forceinline__ float bhi(unsigned v) { return __uint_as_float(v & 0xFFFF0000u); }

// dword index of element `pos` in the (possibly int64) edge array:
// non-negative int64 < 2^31 lives in the low dword.
__device__ __forceinline__ long long didx(long long pos, int is64) {
    return is64 ? 2 * pos : pos;
}

// ---------------------------------------------------------------------------
// int64-vs-int32 edge_index detection (odd dwords all zero => int64)
// ---------------------------------------------------------------------------
__global__ void detect_kernel(const void* __restrict__ ei, int* __restrict__ flag) {
    __shared__ int any;
    if (threadIdx.x == 0) any = 0;
    __syncthreads();
    const int* p = (const int*)ei;
    int nz = 0;
    for (int i = threadIdx.x; i < 2048; i += 256) nz |= (p[2 * i + 1] != 0);
    if (nz) any = 1;
    __syncthreads();
    if (threadIdx.x == 0) flag[0] = any ? 0 : 1;
}

// ---------------------------------------------------------------------------
// fp32 -> bf16 bulk conversion (8 elements / thread)
// ---------------------------------------------------------------------------
__global__ void cvt_kernel(const float* __restrict__ in, unsigned short* __restrict__ out, int n8) {
    int i = blockIdx.x * 256 + threadIdx.x;
    if (i >= n8) return;
    const float4* p = (const float4*)in + (size_t)i * 2;
    float4 a = p[0], b = p[1];
    uint4 o;
    o.x = f2b(a.x) | (f2b(a.y) << 16);
    o.y = f2b(a.z) | (f2b(a.w) << 16);
    o.z = f2b(b.x) | (f2b(b.y) << 16);
    o.w = f2b(b.z) | (f2b(b.w) << 16);
    ((uint4*)out)[i] = o;
}

// all 4 weight matrices in one launch: 4 x 2048 chunks of 8
__global__ void cvtw_kernel(const float* __restrict__ w0, const float* __restrict__ w1,
                            const float* __restrict__ w2, const float* __restrict__ w3,
                            unsigned short* __restrict__ o0, unsigned short* __restrict__ o1,
                            unsigned short* __restrict__ o2, unsigned short* __restrict__ o3) {
    int i = blockIdx.x * 256 + threadIdx.x;      // 0..8191
    int which = i >> 11, j = i & 2047;
    const float* in = which == 0 ? w0 : which == 1 ? w1 : which == 2 ? w2 : w3;
    unsigned short* out = which == 0 ? o0 : which == 1 ? o1 : which == 2 ? o2 : o3;
    const float4* p = (const float4*)in + (size_t)j * 2;
    float4 a = p[0], b = p[1];
    uint4 o;
    o.x = f2b(a.x) | (f2b(a.y) << 16);
    o.y = f2b(a.z) | (f2b(a.w) << 16);
    o.z = f2b(b.x) | (f2b(b.y) << 16);
    o.w = f2b(b.z) | (f2b(b.w) << 16);
    ((uint4*)out)[j] = o;
}

// ---------------------------------------------------------------------------
// Histogram of destination degrees. Non-temporal streaming loads, 8-deep.
// ---------------------------------------------------------------------------
__global__ void hist_kernel(const void* __restrict__ ei, int* __restrict__ deg,
                            const int* __restrict__ flag, int E) {
    int is64 = flag[0];
    const int* p = (const int*)ei;
    int base = blockIdx.x * 2048 + threadIdx.x;
    int d[8];
#pragma unroll
    for (int k = 0; k < 8; k++) {
        int e = base + k * 256;
        d[k] = e < E ? __builtin_nontemporal_load(&p[didx((long long)E + e, is64)]) : -1;
    }
#pragma unroll
    for (int k = 0; k < 8; k++)
        if (d[k] >= 0) atomicAdd(&deg[d[k]], 1);
}

// ---------------------------------------------------------------------------
// Two-level exclusive scan over N
// ---------------------------------------------------------------------------
__global__ void scan1(const int* __restrict__ deg, int* __restrict__ offsets,
                      int* __restrict__ bsum, int n) {
    __shared__ int wsum[4];
    int t = threadIdx.x, lane = t & 63, w = t >> 6;
    int base = blockIdx.x * 1024 + t * 4;
    int a0 = base + 0 < n ? deg[base + 0] : 0;
    int a1 = base + 1 < n ? deg[base + 1] : 0;
    int a2 = base + 2 < n ? deg[base + 2] : 0;
    int a3 = base + 3 < n ? deg[base + 3] : 0;
    int s = a0 + a1 + a2 + a3;
    int x = s;
#pragma unroll
    for (int off = 1; off < 64; off <<= 1) {
        int y = __shfl_up(x, off, 64);
        if (lane >= off) x += y;
    }
    if (lane == 63) wsum[w] = x;
    __syncthreads();
    if (t == 0) {
        int c = 0;
#pragma unroll
        for (int k = 0; k < 4; k++) { int tmp = wsum[k]; wsum[k] = c; c += tmp; }
        bsum[blockIdx.x] = c;
    }
    __syncthreads();
    int excl = wsum[w] + (x - s);
    if (base + 0 < n) offsets[base + 0] = excl;
    if (base + 1 < n) offsets[base + 1] = excl + a0;
    if (base + 2 < n) offsets[base + 2] = excl + a0 + a1;
    if (base + 3 < n) offsets[base + 3] = excl + a0 + a1 + a2;
}

__global__ void scan2(int* __restrict__ bsum, int* __restrict__ offsets, int nb, int n) {
    __shared__ int w0tot;
    int t = threadIdx.x, lane = t & 63, w = t >> 6;
    int v = t < nb ? bsum[t] : 0;
    int x = v;
#pragma unroll
    for (int off = 1; off < 64; off <<= 1) {
        int y = __shfl_up(x, off, 64);
        if (lane >= off) x += y;
    }
    if (t == 63) w0tot = x;
    __syncthreads();
    int excl = x - v + (w ? w0tot : 0);
    if (t < nb) bsum[t] = excl;
    if (t == nb - 1) offsets[n] = excl + v;
}

__global__ void scan3(int* __restrict__ offsets, int* __restrict__ cursor,
                      const int* __restrict__ bsum, int n) {
    int base = blockIdx.x * 1024 + threadIdx.x * 4;
    int add = bsum[blockIdx.x];
#pragma unroll
    for (int j = 0; j < 4; j++) {
        int i = base + j;
        if (i < n) { int v = offsets[i] + add; offsets[i] = v; cursor[i] = v; }
    }
}

// ---------------------------------------------------------------------------
// CSR fill, XCD-aware with bounded exactly-once claiming (pigeonhole CAS).
// NT edge loads (streaming data no longer evicts the csr/cursor write
// frontier from L2) + 8-deep chains + 512 threads/block to hide the
// device-atomic latency.
// ---------------------------------------------------------------------------
__global__ __launch_bounds__(512)
void fill_kernel(const void* __restrict__ ei, int* __restrict__ cursor,
                 int* __restrict__ csr_src, const int* __restrict__ flag,
                 int* __restrict__ claim, int E) {
    const int c = blockIdx.x >> 3;   // chunk
    const int is64 = flag[0];
    const int* p = (const int*)ei;
    const int t = threadIdx.x;

    int xcd;
    asm volatile("s_getreg_b32 %0, hwreg(HW_REG_XCC_ID)" : "=s"(xcd));
    xcd &= 7;

    __shared__ int s_r;
    if (t == 0) {
        int got = -1;
#pragma unroll
        for (int k = 0; k < 8; k++) {
            int r = (xcd + k) & 7;
            if (atomicCAS(&claim[c * 8 + r], 0, 1) == 0) { got = r; break; }
        }
        s_r = got;   // guaranteed >= 0 by pigeonhole
    }
    __syncthreads();
    const int r = s_r;
    if (r < 0) return;  // unreachable; defensive

    const int lo = r * (NN / 8), hi = lo + (NN / 8);
    const int beg = c * FILL_CHUNK;
    const int end = min(beg + FILL_CHUNK, E);
    for (int i = beg + t; i < end; i += 4096) {
        int d[8];
#pragma unroll
        for (int k = 0; k < 8; k++) {
            int e = i + k * 512;
            d[k] = e < end ? __builtin_nontemporal_load(&p[didx((long long)E + e, is64)]) : -1;
        }
#pragma unroll
        for (int k = 0; k < 8; k++) {
            if (d[k] >= lo && d[k] < hi) {
                int e = i + k * 512;
                int s = __builtin_nontemporal_load(&p[didx(e, is64)]);
                csr_src[atomicAdd(&cursor[d[k]], 1)] = s;
            }
        }
    }
}

// ---------------------------------------------------------------------------
// bf16 aggregation: 1 wave per node, lane owns 2 dims (one packed uint).
// csr indices are a read-once stream -> non-temporal; h rows stay cached.
// ---------------------------------------------------------------------------
__global__ void agg_kernel(const unsigned* __restrict__ hb,
                           const int* __restrict__ offsets,
                           const int* __restrict__ csr,
                           unsigned* __restrict__ aggb, int n) {
    int node = blockIdx.x * 4 + (threadIdx.x >> 6);
    int lane = threadIdx.x & 63;
    if (node >= n) return;
    int e = offsets[node], end = offsets[node + 1];
    float lo4[4] = {0.f, 0.f, 0.f, 0.f}, hi4[4] = {0.f, 0.f, 0.f, 0.f};
    for (; e + 8 <= end; e += 8) {
        int idx[8];
        unsigned vv[8];
#pragma unroll
        for (int j = 0; j < 8; j++) idx[j] = __builtin_nontemporal_load(&csr[e + j]);
#pragma unroll
        for (int j = 0; j < 8; j++) vv[j] = hb[idx[j] * 64 + lane];
#pragma unroll
        for (int j = 0; j < 8; j++) { lo4[j & 3] += blo(vv[j]); hi4[j & 3] += bhi(vv[j]); }
    }
    for (; e + 4 <= end; e += 4) {
        int idx[4];
        unsigned vv[4];
#pragma unroll
        for (int j = 0; j < 4; j++) idx[j] = __builtin_nontemporal_load(&csr[e + j]);
#pragma unroll
        for (int j = 0; j < 4; j++) vv[j] = hb[idx[j] * 64 + lane];
#pragma unroll
        for (int j = 0; j < 4; j++) { lo4[j] += blo(vv[j]); hi4[j] += bhi(vv[j]); }
    }
    for (; e < end; ++e) {
        unsigned v = hb[csr[e] * 64 + lane];
        lo4[0] += blo(v); hi4[0] += bhi(v);
    }
    float s0 = (lo4[0] + lo4[1]) + (lo4[2] + lo4[3]);
    float s1 = (hi4[0] + hi4[1]) + (hi4[2] + hi4[3]);
    aggb[node * 64 + lane] = f2b(s0) | (f2b(s1) << 16);
}

// ---------------------------------------------------------------------------
// MFMA bf16 GEMM: out = A@Wr^T + H@Wt^T + bias (+relu for bf16 output).
// 128x128 tile per block, 4 waves; XOR-swizzled LDS.
// ---------------------------------------------------------------------------
template <int OUTF32>
__global__ __launch_bounds__(256, 2)
void mfma_gemm(const unsigned short* __restrict__ A,
               const unsigned short* __restrict__ H,
               const unsigned short* __restrict__ Wr,
               const unsigned short* __restrict__ Wt,
               const float* __restrict__ bias,
               void* __restrict__ outp, int n) {
    __shared__ __align__(16) char sIn[128 * 256];
    __shared__ __align__(16) char sW[128 * 256];
    int t = threadIdx.x;
    int l = t & 63, w = t >> 6;
    int row0 = blockIdx.x * 128;
    int lr = l & 15;
    int lk = (l >> 4) << 3;  // 0,8,16,24

    f32x4 acc[2][8];
#pragma unroll
    for (int i = 0; i < 2; i++)
#pragma unroll
        for (int j = 0; j < 8; j++) acc[i][j] = (f32x4){0.f, 0.f, 0.f, 0.f};

    for (int phase = 0; phase < 2; ++phase) {
        const unsigned short* In = phase ? H : A;
        const unsigned short* W = phase ? Wt : Wr;
        __syncthreads();  // previous phase done reading LDS
#pragma unroll
        for (int q = 0; q < 8; q++) {
            int idx = q * 256 + t;
            int r = idx >> 4, c = idx & 15;  // 128 rows x 16 chunks of 16B
            int gr = row0 + r; if (gr > n - 1) gr = n - 1;
            uint4 v = ((const uint4*)In)[(size_t)gr * 16 + c];
            *(uint4*)(sIn + r * 256 + ((c * 16) ^ ((r & 7) << 4))) = v;
            uint4 wv = ((const uint4*)W)[r * 16 + c];
            *(uint4*)(sW + r * 256 + ((c * 16) ^ ((r & 7) << 4))) = wv;
        }
        __syncthreads();
#pragma unroll
        for (int ks = 0; ks < 4; ++ks) {
            int kb = (ks * 32 + lk) * 2;  // byte offset of k within row
            short8 av[2], bv[8];
#pragma unroll
            for (int mt = 0; mt < 2; mt++) {
                int r = w * 32 + mt * 16 + lr;
                av[mt] = *(const short8*)(sIn + r * 256 + (kb ^ ((r & 7) << 4)));
            }
#pragma unroll
            for (int nt = 0; nt < 8; nt++) {
                int cw = nt * 16 + lr;
                bv[nt] = *(const short8*)(sW + cw * 256 + (kb ^ ((cw & 7) << 4)));
            }
#pragma unroll
            for (int mt = 0; mt < 2; mt++)
#pragma unroll
                for (int nt = 0; nt < 8; nt++)
                    acc[mt][nt] = __builtin_amdgcn_mfma_f32_16x16x32_bf16(
                        av[mt], bv[nt], acc[mt][nt], 0, 0, 0);
        }
    }

    // C/D layout (m89-verified): col = lane&15, row = (lane>>4)*4 + reg
    int rbase = row0 + w * 32 + ((l >> 4) << 2);
#pragma unroll
    for (int mt = 0; mt < 2; mt++) {
#pragma unroll
        for (int nt = 0; nt < 8; nt++) {
            int col = nt * 16 + lr;
            float bc = bias[col];
#pragma unroll
            for (int j = 0; j < 4; j++) {
                int row = rbase + mt * 16 + j;
                if (row < n) {
                    float v = acc[mt][nt][j] + bc;
                    if (OUTF32) {
                        ((float*)outp)[(size_t)row * DIM + col] = v;
                    } else {
                        v = fmaxf(v, 0.f);
                        ((unsigned short*)outp)[(size_t)row * DIM + col] =
                            (unsigned short)f2b(v);
                    }
                }
            }
        }
    }
}

// ---------------------------------------------------------------------------
extern "C" void kernel_launch(void* const* d_in, const int* in_sizes, int n_in,
                              void* d_out, int out_size, void* d_ws, size_t ws_size,
                              hipStream_t stream) {
    const int N = NN, E = NE;
    const float* x = (const float*)d_in[0];
    const void* ei = d_in[1];
    const float* W1r = (const float*)d_in[2];
    const float* W1t = (const float*)d_in[3];
    const float* b1 = (const float*)d_in[4];
    const float* W2r = (const float*)d_in[5];
    const float* W2t = (const float*)d_in[6];
    const float* b2 = (const float*)d_in[7];
    float* out = (float*)d_out;

    char* wsp = (char*)d_ws;
    auto alloc = [&](size_t bytes) {
        char* p = wsp;
        wsp += (bytes + 255) & ~(size_t)255;
        return p;
    };
    int* flag = (int*)alloc(4);
    int* deg = (int*)alloc((size_t)N * 4);
    int* claim = (int*)alloc((size_t)NCHUNK * 8 * 4);
    int* offsets = (int*)alloc((size_t)(N + 1) * 4);
    int* cursor = (int*)alloc((size_t)N * 4);
    int* bsum = (int*)alloc(512);
    int* csr_src = (int*)alloc((size_t)E * 4);
    unsigned short* w1rb = (unsigned short*)alloc(DIM * DIM * 2);
    unsigned short* w1tb = (unsigned short*)alloc(DIM * DIM * 2);
    unsigned short* w2rb = (unsigned short*)alloc(DIM * DIM * 2);
    unsigned short* w2tb = (unsigned short*)alloc(DIM * DIM * 2);
    unsigned short* xb = (unsigned short*)alloc((size_t)N * DIM * 2);   // becomes h (bf16)
    unsigned short* aggb = (unsigned short*)alloc((size_t)N * DIM * 2); // agg1 then agg2

    const int NB = (N + 1023) / 1024;  // 98

    hipMemsetAsync(deg, 0, (size_t)N * 4, stream);
    hipMemsetAsync(claim, 0, (size_t)NCHUNK * 8 * 4, stream);
    detect_kernel<<<1, 256, 0, stream>>>(ei, flag);

    // bf16 conversions (independent of CSR build)
    cvt_kernel<<<(N * DIM / 8 + 255) / 256, 256, 0, stream>>>(x, xb, N * DIM / 8);
    cvtw_kernel<<<32, 256, 0, stream>>>(W1r, W1t, W2r, W2t, w1rb, w1tb, w2rb, w2tb);

    // CSR by destination
    hist_kernel<<<(E + 2047) / 2048, 256, 0, stream>>>(ei, deg, flag, E);
    scan1<<<NB, 256, 0, stream>>>(deg, offsets, bsum, N);
    scan2<<<1, 128, 0, stream>>>(bsum, offsets, NB, N);
    scan3<<<NB, 256, 0, stream>>>(offsets, cursor, bsum, N);
    fill_kernel<<<NCHUNK * 8, 512, 0, stream>>>(ei, cursor, csr_src, flag, claim, E);

    // Layer 1: agg1 = segsum(xb); h = relu(agg1@W1r^T + x@W1t^T + b1) -> xb (bf16)
    agg_kernel<<<N / 4, 256, 0, stream>>>((const unsigned*)xb, offsets, csr_src,
                                          (unsigned*)aggb, N);
    mfma_gemm<0><<<(N + 127) / 128, 256, 0, stream>>>(aggb, xb, w1rb, w1tb, b1, xb, N);

    // Layer 2: agg2 = segsum(h); out = agg2@W2r^T + h@W2t^T + b2 (fp32)
    agg_kernel<<<N / 4, 256, 0, stream>>>((const unsigned*)xb, offsets, csr_src,
                                          (unsigned*)aggb, N);
    mfma_gemm<1><<<(N + 127) / 128, 256, 0, stream>>>(aggb, xb, w2rb, w2tb, b2, out, N);
}

// Round 14
// 366.224 us; speedup vs baseline: 1.2492x; 1.2492x over previous
//
#include <hip/hip_runtime.h>

#define NN 100000
#define DIM 128
#define NE 1600000
#define BINW 128
#define NBIN 782            // ceil(NN / BINW)
#define NSB 64              // scatter blocks
#define SCHUNK (NE / NSB)   // 25000

typedef __attribute__((ext_vector_type(8))) short short8;
typedef __attribute__((ext_vector_type(4))) float f32x4;

// fp32 -> bf16 bits, round-to-nearest-even
__device__ __forceinline__ unsigned f2b(float f) {
    unsigned u = __float_as_uint(f);
    return (u + 0x7FFFu + ((u >> 16) & 1u)) >> 16;
}
__device__ __forceinline__ float blo(unsigned v) { return __uint_as_float(v << 16); }
__device__ __forceinline__ float bhi(unsigned v) { return __uint_as_float(v & 0xFFFF0000u); }

// dword index of element `pos` in the (possibly int64) edge array:
// non-negative int64 < 2^31 lives in the low dword.
__device__ __forceinline__ long long didx(long long pos, int is64) {
    return is64 ? 2 * pos : pos;
}

// ---------------------------------------------------------------------------
// int64-vs-int32 edge_index detection (odd dwords all zero => int64)
// ---------------------------------------------------------------------------
__global__ void detect_kernel(const void* __restrict__ ei, int* __restrict__ flag) {
    __shared__ int any;
    if (threadIdx.x == 0) any = 0;
    __syncthreads();
    const int* p = (const int*)ei;
    int nz = 0;
    for (int i = threadIdx.x; i < 2048; i += 256) nz |= (p[2 * i + 1] != 0);
    if (nz) any = 1;
    __syncthreads();
    if (threadIdx.x == 0) flag[0] = any ? 0 : 1;
}

// ---------------------------------------------------------------------------
// fp32 -> bf16 bulk conversion (8 elements / thread)
// ---------------------------------------------------------------------------
__global__ void cvt_kernel(const float* __restrict__ in, unsigned short* __restrict__ out, int n8) {
    int i = blockIdx.x * 256 + threadIdx.x;
    if (i >= n8) return;
    const float4* p = (const float4*)in + (size_t)i * 2;
    float4 a = p[0], b = p[1];
    uint4 o;
    o.x = f2b(a.x) | (f2b(a.y) << 16);
    o.y = f2b(a.z) | (f2b(a.w) << 16);
    o.z = f2b(b.x) | (f2b(b.y) << 16);
    o.w = f2b(b.z) | (f2b(b.w) << 16);
    ((uint4*)out)[i] = o;
}

// all 4 weight matrices in one launch: 4 x 2048 chunks of 8
__global__ void cvtw_kernel(const float* __restrict__ w0, const float* __restrict__ w1,
                            const float* __restrict__ w2, const float* __restrict__ w3,
                            unsigned short* __restrict__ o0, unsigned short* __restrict__ o1,
                            unsigned short* __restrict__ o2, unsigned short* __restrict__ o3) {
    int i = blockIdx.x * 256 + threadIdx.x;      // 0..8191
    int which = i >> 11, j = i & 2047;
    const float* in = which == 0 ? w0 : which == 1 ? w1 : which == 2 ? w2 : w3;
    unsigned short* out = which == 0 ? o0 : which == 1 ? o1 : which == 2 ? o2 : o3;
    const float4* p = (const float4*)in + (size_t)j * 2;
    float4 a = p[0], b = p[1];
    uint4 o;
    o.x = f2b(a.x) | (f2b(a.y) << 16);
    o.y = f2b(a.z) | (f2b(a.w) << 16);
    o.z = f2b(b.x) | (f2b(b.y) << 16);
    o.w = f2b(b.z) | (f2b(b.w) << 16);
    ((uint4*)out)[j] = o;
}

// ---------------------------------------------------------------------------
// S1: per-block histogram of 128-node bins (dst>>7). LDS atomics only.
// Bin index clamped defensively (cannot change correct-input results).
// ---------------------------------------------------------------------------
__global__ __launch_bounds__(512)
void binhist_kernel(const void* __restrict__ ei, const int* __restrict__ flag,
                    int* __restrict__ bcnt) {
    __shared__ int h[NBIN];
    for (int k = threadIdx.x; k < NBIN; k += 512) h[k] = 0;
    __syncthreads();
    const int is64 = flag[0];
    const int* p = (const int*)ei;
    const int beg = blockIdx.x * SCHUNK, end = beg + SCHUNK;
    for (int i = beg + (int)threadIdx.x; i < end; i += 512) {
        unsigned b = ((unsigned)p[didx((long long)NE + i, is64)]) >> 7;
        if (b < NBIN) atomicAdd(&h[b], 1);
    }
    __syncthreads();
    for (int k = threadIdx.x; k < NBIN; k += 512)
        bcnt[blockIdx.x * NBIN + k] = h[k];
}

// ---------------------------------------------------------------------------
// S2: exact per-(block,bin) start positions. Single block.
// start[b][k] = binofs[k] + sum_{b'<b} bcnt[b'][k];  binofs = excl scan of totals.
// ---------------------------------------------------------------------------
__global__ __launch_bounds__(1024)
void binscan_kernel(const int* __restrict__ bcnt, int* __restrict__ start,
                    int* __restrict__ binofs) {
    __shared__ int tot[NBIN];
    __shared__ int wsum[16];
    int t = threadIdx.x, lane = t & 63, w = t >> 6;
    for (int k = t; k < NBIN; k += 1024) {
        int s = 0;
        for (int b = 0; b < NSB; b++) s += bcnt[b * NBIN + k];
        tot[k] = s;
    }
    __syncthreads();
    int v = (t < NBIN) ? tot[t] : 0;
    int x = v;
#pragma unroll
    for (int off = 1; off < 64; off <<= 1) {
        int y = __shfl_up(x, off, 64);
        if (lane >= off) x += y;
    }
    if (lane == 63) wsum[w] = x;
    __syncthreads();
    if (w == 0) {
        int s = (lane < 16) ? wsum[lane] : 0;
#pragma unroll
        for (int off = 1; off < 16; off <<= 1) {
            int y = __shfl_up(s, off, 64);
            if (lane >= off) s += y;
        }
        if (lane < 16) wsum[lane] = s;
    }
    __syncthreads();
    int excl = (w ? wsum[w - 1] : 0) + (x - v);
    if (t < NBIN) binofs[t] = excl;
    if (t == NBIN - 1) binofs[NBIN] = excl + v;
    __syncthreads();
    for (int k = t; k < NBIN; k += 1024) {
        int acc = binofs[k];
        for (int b = 0; b < NSB; b++) {
            start[b * NBIN + k] = acc;
            acc += bcnt[b * NBIN + k];
        }
    }
}

// ---------------------------------------------------------------------------
// S3: scatter edges into bin-grouped code array. Each (block,bin) segment is
// EXCLUSIVE (exact counts from S1/S2). code = (dst&127)<<17 | src (src<2^17).
// All writes clamped to [0,NE) defensively.
// ---------------------------------------------------------------------------
__global__ __launch_bounds__(512)
void binscatter_kernel(const void* __restrict__ ei, const int* __restrict__ flag,
                       const int* __restrict__ start, unsigned* __restrict__ ebin) {
    __shared__ int cur[NBIN];
    for (int k = threadIdx.x; k < NBIN; k += 512)
        cur[k] = start[blockIdx.x * NBIN + k];
    __syncthreads();
    const int is64 = flag[0];
    const int* p = (const int*)ei;
    const int beg = blockIdx.x * SCHUNK, end = beg + SCHUNK;
    for (int i = beg + (int)threadIdx.x; i < end; i += 2048) {
        int dd[4], ss[4];
#pragma unroll
        for (int j = 0; j < 4; j++) {
            int e = i + j * 512;
            if (e < end) {
                dd[j] = p[didx((long long)NE + e, is64)];
                ss[j] = p[didx(e, is64)];
            } else { dd[j] = -1; ss[j] = 0; }
        }
#pragma unroll
        for (int j = 0; j < 4; j++) {
            unsigned b = ((unsigned)dd[j]) >> 7;
            if (dd[j] >= 0 && b < NBIN) {
                int pos = atomicAdd(&cur[b], 1);
                if ((unsigned)pos < (unsigned)NE)
                    ebin[pos] = ((unsigned)(dd[j] & 127) << 17) | (unsigned)ss[j];
            }
        }
    }
}

// ---------------------------------------------------------------------------
// S4: finalize per-node CSR within each bin. One block per bin; the bin's
// ~2K-edge segment is an 8KB L2-exclusive window -> cheap local scatter.
// Produces the same offsets/csr format the aggregation always used.
// ---------------------------------------------------------------------------
__global__ __launch_bounds__(256)
void binfin_kernel(const unsigned* __restrict__ ebin, const int* __restrict__ binofs,
                   int* __restrict__ offsets, int* __restrict__ csr) {
    __shared__ int cnt[BINW];
    __shared__ int excl[BINW];
    int t = threadIdx.x;
    if (t < BINW) cnt[t] = 0;
    __syncthreads();
    int k = blockIdx.x;
    int beg = binofs[k];
    int end = binofs[k + 1];
    if (beg < 0) beg = 0;
    if (end > NE) end = NE;           // defensive
    for (int i = beg + t; i < end; i += 256) atomicAdd(&cnt[ebin[i] >> 17], 1);
    __syncthreads();
    if (t == 0) {
        int a = 0;
        for (int r = 0; r < BINW; r++) { excl[r] = a; a += cnt[r]; }
    }
    __syncthreads();
    if (t < BINW) {
        int node = k * BINW + t;
        if (node < NN) offsets[node] = beg + excl[t];
        cnt[t] = excl[t];            // reuse as local cursor
    }
    if (k == 0 && t == 0) offsets[NN] = NE;
    __syncthreads();
    for (int i = beg + t; i < end; i += 256) {
        unsigned c = ebin[i];
        int pos = atomicAdd(&cnt[c >> 17], 1);
        if (beg + pos < NE) csr[beg + pos] = (int)(c & 0x1FFFF);
    }
}

// ---------------------------------------------------------------------------
// bf16 aggregation: 1 wave per node, lane owns 2 dims (one packed uint).
// 8-deep independent gathers; cached csr loads.
// ---------------------------------------------------------------------------
__global__ void agg_kernel(const unsigned* __restrict__ hb,
                           const int* __restrict__ offsets,
                           const int* __restrict__ csr,
                           unsigned* __restrict__ aggb, int n) {
    int node = blockIdx.x * 4 + (threadIdx.x >> 6);
    int lane = threadIdx.x & 63;
    if (node >= n) return;
    int e = offsets[node], end = offsets[node + 1];
    float lo4[4] = {0.f, 0.f, 0.f, 0.f}, hi4[4] = {0.f, 0.f, 0.f, 0.f};
    for (; e + 8 <= end; e += 8) {
        int idx[8];
        unsigned vv[8];
#pragma unroll
        for (int j = 0; j < 8; j++) idx[j] = csr[e + j];
#pragma unroll
        for (int j = 0; j < 8; j++) vv[j] = hb[idx[j] * 64 + lane];
#pragma unroll
        for (int j = 0; j < 8; j++) { lo4[j & 3] += blo(vv[j]); hi4[j & 3] += bhi(vv[j]); }
    }
    for (; e + 4 <= end; e += 4) {
        int idx[4];
        unsigned vv[4];
#pragma unroll
        for (int j = 0; j < 4; j++) idx[j] = csr[e + j];
#pragma unroll
        for (int j = 0; j < 4; j++) vv[j] = hb[idx[j] * 64 + lane];
#pragma unroll
        for (int j = 0; j < 4; j++) { lo4[j] += blo(vv[j]); hi4[j] += bhi(vv[j]); }
    }
    for (; e < end; ++e) {
        unsigned v = hb[csr[e] * 64 + lane];
        lo4[0] += blo(v); hi4[0] += bhi(v);
    }
    float s0 = (lo4[0] + lo4[1]) + (lo4[2] + lo4[3]);
    float s1 = (hi4[0] + hi4[1]) + (hi4[2] + hi4[3]);
    aggb[node * 64 + lane] = f2b(s0) | (f2b(s1) << 16);
}

// ---------------------------------------------------------------------------
// MFMA bf16 GEMM: out = A@Wr^T + H@Wt^T + bias (+relu for bf16 output).
// 128x128 tile per block, 4 waves; XOR-swizzled LDS.
// ---------------------------------------------------------------------------
template <int OUTF32>
__global__ __launch_bounds__(256, 2)
void mfma_gemm(const unsigned short* __restrict__ A,
               const unsigned short* __restrict__ H,
               const unsigned short* __restrict__ Wr,
               const unsigned short* __restrict__ Wt,
               const float* __restrict__ bias,
               void* __restrict__ outp, int n) {
    __shared__ __align__(16) char sIn[128 * 256];
    __shared__ __align__(16) char sW[128 * 256];
    int t = threadIdx.x;
    int l = t & 63, w = t >> 6;
    int row0 = blockIdx.x * 128;
    int lr = l & 15;
    int lk = (l >> 4) << 3;  // 0,8,16,24

    f32x4 acc[2][8];
#pragma unroll
    for (int i = 0; i < 2; i++)
#pragma unroll
        for (int j = 0; j < 8; j++) acc[i][j] = (f32x4){0.f, 0.f, 0.f, 0.f};

    for (int phase = 0; phase < 2; ++phase) {
        const unsigned short* In = phase ? H : A;
        const unsigned short* W = phase ? Wt : Wr;
        __syncthreads();  // previous phase done reading LDS
#pragma unroll
        for (int q = 0; q < 8; q++) {
            int idx = q * 256 + t;
            int r = idx >> 4, c = idx & 15;  // 128 rows x 16 chunks of 16B
            int gr = row0 + r; if (gr > n - 1) gr = n - 1;
            uint4 v = ((const uint4*)In)[(size_t)gr * 16 + c];
            *(uint4*)(sIn + r * 256 + ((c * 16) ^ ((r & 7) << 4))) = v;
            uint4 wv = ((const uint4*)W)[r * 16 + c];
            *(uint4*)(sW + r * 256 + ((c * 16) ^ ((r & 7) << 4))) = wv;
        }
        __syncthreads();
#pragma unroll
        for (int ks = 0; ks < 4; ++ks) {
            int kb = (ks * 32 + lk) * 2;  // byte offset of k within row
            short8 av[2], bv[8];
#pragma unroll
            for (int mt = 0; mt < 2; mt++) {
                int r = w * 32 + mt * 16 + lr;
                av[mt] = *(const short8*)(sIn + r * 256 + (kb ^ ((r & 7) << 4)));
            }
#pragma unroll
            for (int nt = 0; nt < 8; nt++) {
                int cw = nt * 16 + lr;
                bv[nt] = *(const short8*)(sW + cw * 256 + (kb ^ ((cw & 7) << 4)));
            }
#pragma unroll
            for (int mt = 0; mt < 2; mt++)
#pragma unroll
                for (int nt = 0; nt < 8; nt++)
                    acc[mt][nt] = __builtin_amdgcn_mfma_f32_16x16x32_bf16(
                        av[mt], bv[nt], acc[mt][nt], 0, 0, 0);
        }
    }

    // C/D layout (m89-verified): col = lane&15, row = (lane>>4)*4 + reg
    int rbase = row0 + w * 32 + ((l >> 4) << 2);
#pragma unroll
    for (int mt = 0; mt < 2; mt++) {
#pragma unroll
        for (int nt = 0; nt < 8; nt++) {
            int col = nt * 16 + lr;
            float bc = bias[col];
#pragma unroll
            for (int j = 0; j < 4; j++) {
                int row = rbase + mt * 16 + j;
                if (row < n) {
                    float v = acc[mt][nt][j] + bc;
                    if (OUTF32) {
                        ((float*)outp)[(size_t)row * DIM + col] = v;
                    } else {
                        v = fmaxf(v, 0.f);
                        ((unsigned short*)outp)[(size_t)row * DIM + col] =
                            (unsigned short)f2b(v);
                    }
                }
            }
        }
    }
}

// ---------------------------------------------------------------------------
extern "C" void kernel_launch(void* const* d_in, const int* in_sizes, int n_in,
                              void* d_out, int out_size, void* d_ws, size_t ws_size,
                              hipStream_t stream) {
    const int N = NN;
    const float* x = (const float*)d_in[0];
    const void* ei = d_in[1];
    const float* W1r = (const float*)d_in[2];
    const float* W1t = (const float*)d_in[3];
    const float* b1 = (const float*)d_in[4];
    const float* W2r = (const float*)d_in[5];
    const float* W2t = (const float*)d_in[6];
    const float* b2 = (const float*)d_in[7];
    float* out = (float*)d_out;

    char* wsp = (char*)d_ws;
    auto alloc = [&](size_t bytes) {
        char* p = wsp;
        wsp += (bytes + 255) & ~(size_t)255;
        return p;
    };
    int* flag = (int*)alloc(4);
    int* bcnt = (int*)alloc((size_t)NSB * NBIN * 4);
    int* start = (int*)alloc((size_t)NSB * NBIN * 4);
    int* binofs = (int*)alloc((size_t)(NBIN + 1) * 4);
    int* offsets = (int*)alloc((size_t)(N + 1) * 4);
    int* csr = (int*)alloc((size_t)NE * 4);
    unsigned short* w1rb = (unsigned short*)alloc(DIM * DIM * 2);
    unsigned short* w1tb = (unsigned short*)alloc(DIM * DIM * 2);
    unsigned short* w2rb = (unsigned short*)alloc(DIM * DIM * 2);
    unsigned short* w2tb = (unsigned short*)alloc(DIM * DIM * 2);
    unsigned short* xb = (unsigned short*)alloc((size_t)N * DIM * 2);   // becomes h (bf16)
    unsigned short* aggb = (unsigned short*)alloc((size_t)N * DIM * 2); // agg1 then agg2
    // ebin aliases aggb: stream-serial lifetimes don't overlap
    // (ebin: binscatter->binfin; aggb: agg1 onward). Keeps ws under the
    // budget proven working in r10 (~59 MB).
    unsigned* ebin = (unsigned*)aggb;

    detect_kernel<<<1, 256, 0, stream>>>(ei, flag);

    // bf16 conversions (independent of CSR build)
    cvt_kernel<<<(N * DIM / 8 + 255) / 256, 256, 0, stream>>>(x, xb, N * DIM / 8);
    cvtw_kernel<<<32, 256, 0, stream>>>(W1r, W1t, W2r, W2t, w1rb, w1tb, w2rb, w2tb);

    // bin-granular CSR build
    binhist_kernel<<<NSB, 512, 0, stream>>>(ei, flag, bcnt);
    binscan_kernel<<<1, 1024, 0, stream>>>(bcnt, start, binofs);
    binscatter_kernel<<<NSB, 512, 0, stream>>>(ei, flag, start, ebin);
    binfin_kernel<<<NBIN, 256, 0, stream>>>(ebin, binofs, offsets, csr);

    // Layer 1: agg1 = segsum(xb); h = relu(agg1@W1r^T + x@W1t^T + b1) -> xb (bf16)
    agg_kernel<<<N / 4, 256, 0, stream>>>((const unsigned*)xb, offsets, csr,
                                          (unsigned*)aggb, N);
    mfma_gemm<0><<<(N + 127) / 128, 256, 0, stream>>>(aggb, xb, w1rb, w1tb, b1, xb, N);

    // Layer 2: agg2 = segsum(h); out = agg2@W2r^T + h@W2t^T + b2 (fp32)
    agg_kernel<<<N / 4, 256, 0, stream>>>((const unsigned*)xb, offsets, csr,
                                          (unsigned*)aggb, N);
    mfma_gemm<1><<<(N + 127) / 128, 256, 0, stream>>>(aggb, xb, w2rb, w2tb, b2, out, N);
}